// Round 1
// baseline (424.631 us; speedup 1.0000x reference)
//
#include <hip/hip_runtime.h>

#define DIM 512
#define QKD 128
#define BATCH 4
#define SEQ 4096

typedef __attribute__((ext_vector_type(8))) _Float16 f16x8;
typedef __attribute__((ext_vector_type(4))) float f32x4;

// ---------------------------------------------------------------------------
// Kernel A: LayerNorm + Linear(512->128) + SiLU + OffsetScale -> q,k (fp16)
// 32 rows per block, 256 threads (4 waves).
// Folds 1/sqrt(4096) = 1/64 as 1/8 into BOTH q and k (exact pow2 scaling).
// ---------------------------------------------------------------------------
__global__ __launch_bounds__(256) void ln_qk_kernel(
    const float* __restrict__ x,
    const float* __restrict__ ln_w,
    const float* __restrict__ ln_b,
    const float* __restrict__ w_qk,
    const float* __restrict__ b_qk,
    const float* __restrict__ gamma,
    const float* __restrict__ beta,
    _Float16* __restrict__ q_h,
    _Float16* __restrict__ k_h)
{
    __shared__ _Float16 As[32][520];   // padded stride breaks bank aliasing
    const int tid  = threadIdx.x;
    const int wave = tid >> 6;
    const int lane = tid & 63;
    const int row0 = blockIdx.x * 32;

    // per-lane LN params for d = lane*8 .. +7
    float lw[8], lb[8];
    {
        const float4* w4 = (const float4*)ln_w;
        const float4* b4 = (const float4*)ln_b;
        float4 w0 = w4[lane * 2], w1 = w4[lane * 2 + 1];
        float4 b0 = b4[lane * 2], b1 = b4[lane * 2 + 1];
        lw[0]=w0.x; lw[1]=w0.y; lw[2]=w0.z; lw[3]=w0.w;
        lw[4]=w1.x; lw[5]=w1.y; lw[6]=w1.z; lw[7]=w1.w;
        lb[0]=b0.x; lb[1]=b0.y; lb[2]=b0.z; lb[3]=b0.w;
        lb[4]=b1.x; lb[5]=b1.y; lb[6]=b1.z; lb[7]=b1.w;
    }

    // LayerNorm: each wave handles 8 rows
    for (int rr = 0; rr < 8; ++rr) {
        const int r = wave * 8 + rr;
        const float4* xr = (const float4*)(x + (size_t)(row0 + r) * DIM);
        float4 v0 = xr[lane * 2], v1 = xr[lane * 2 + 1];
        float xv[8] = {v0.x, v0.y, v0.z, v0.w, v1.x, v1.y, v1.z, v1.w};
        float s = 0.f, s2 = 0.f;
#pragma unroll
        for (int j = 0; j < 8; ++j) { s += xv[j]; s2 = fmaf(xv[j], xv[j], s2); }
#pragma unroll
        for (int off = 32; off > 0; off >>= 1) {
            s  += __shfl_xor(s,  off);
            s2 += __shfl_xor(s2, off);
        }
        const float mu   = s * (1.f / DIM);
        const float var  = s2 * (1.f / DIM) - mu * mu;
        const float rstd = rsqrtf(var + 1e-5f);
        f16x8 h;
#pragma unroll
        for (int j = 0; j < 8; ++j)
            h[j] = (_Float16)(fmaf((xv[j] - mu) * rstd, lw[j], lb[j]));
        *(f16x8*)&As[r][lane * 8] = h;
    }
    __syncthreads();

    // GEMM: M=32 (2 m-tiles), N=128 (2 n-halves of 64).
    // wave: mtile = wave&1, nbase = (wave>>1)*64
    const int mtile = wave & 1;
    const int nbase = (wave >> 1) * 64;
    const int lcol  = lane & 15;
    const int quad  = lane >> 4;

    f32x4 acc[4];
#pragma unroll
    for (int nt = 0; nt < 4; ++nt) acc[nt] = (f32x4){0.f, 0.f, 0.f, 0.f};

    const _Float16* arow = &As[mtile * 16 + lcol][quad * 8];
#pragma unroll 4
    for (int kc = 0; kc < 16; ++kc) {
        const f16x8 af = *(const f16x8*)(arow + kc * 32);
#pragma unroll
        for (int nt = 0; nt < 4; ++nt) {
            const int e = nbase + nt * 16 + lcol;
            const float* wp = w_qk + (size_t)e * DIM + kc * 32 + quad * 8;
            const float4 w0 = *(const float4*)wp;
            const float4 w1 = *(const float4*)(wp + 4);
            f16x8 bfr;
            bfr[0]=(_Float16)w0.x; bfr[1]=(_Float16)w0.y; bfr[2]=(_Float16)w0.z; bfr[3]=(_Float16)w0.w;
            bfr[4]=(_Float16)w1.x; bfr[5]=(_Float16)w1.y; bfr[6]=(_Float16)w1.z; bfr[7]=(_Float16)w1.w;
            acc[nt] = __builtin_amdgcn_mfma_f32_16x16x32_f16(af, bfr, acc[nt], 0, 0, 0);
        }
    }

    // epilogue: bias + SiLU + offset-scale (scaled by 1/8), store fp16
#pragma unroll
    for (int nt = 0; nt < 4; ++nt) {
        const int e = nbase + nt * 16 + lcol;
        const float bq  = b_qk[e];
        const float g0  = gamma[e]       * 0.125f;
        const float g1  = gamma[QKD + e] * 0.125f;
        const float be0 = beta[e]        * 0.125f;
        const float be1 = beta[QKD + e]  * 0.125f;
#pragma unroll
        for (int reg = 0; reg < 4; ++reg) {
            const int m  = mtile * 16 + quad * 4 + reg;
            const float v   = acc[nt][reg] + bq;
            const float sil = v / (1.f + __expf(-v));
            const size_t off = (size_t)(row0 + m) * QKD + e;
            q_h[off] = (_Float16)fmaf(sil, g0, be0);
            k_h[off] = (_Float16)fmaf(sil, g1, be1);
        }
    }
}

// ---------------------------------------------------------------------------
// Kernel B: sim = q.k^T (already includes 1/64), attn = relu(sim)^2 row-norm.
// 64 rows/block, 256 blocks (1/CU). Two-pass recompute: pass1 rowsums,
// pass2 recompute + scale + store. q frags register-resident; k frags
// global-loaded (L2-resident per XCD via batch swizzle) with prefetch.
// ---------------------------------------------------------------------------
__global__ __launch_bounds__(256) void attn_kernel(
    const _Float16* __restrict__ q_h,
    const _Float16* __restrict__ k_h,
    float* __restrict__ out)
{
    // XCD-aware swizzle: linear id l -> xcd = l&7 (round-robin heuristic);
    // give each XCD a single batch so its k (1 MB) stays L2-resident.
    const int l     = blockIdx.x;
    const int batch = (l & 7) >> 1;
    const int tile  = ((l >> 3) << 1) | (l & 1);

    const int wave = threadIdx.x >> 6;
    const int lane = threadIdx.x & 63;
    const int lcol = lane & 15;
    const int quad = lane >> 4;
    const int r0   = tile * 64;

    const _Float16* qb = q_h + ((size_t)batch * SEQ + r0) * QKD;
    // per-lane k base: col = wave*16 + lcol (within 64-col tile), k-chunk quad*8
    const _Float16* kb = k_h + (size_t)batch * SEQ * QKD
                             + (size_t)(wave * 16 + lcol) * QKD + quad * 8;

    // q fragments: 4 m-tiles x 4 k-chunks, register resident (64 VGPRs)
    f16x8 aq[4][4];
#pragma unroll
    for (int mt = 0; mt < 4; ++mt)
#pragma unroll
        for (int kc = 0; kc < 4; ++kc)
            aq[mt][kc] = *(const f16x8*)(qb + (size_t)(mt * 16 + lcol) * QKD + kc * 32 + quad * 8);

    __shared__ float partial[4][64];
    __shared__ float scale_s[64];

    float rs[4][4];
#pragma unroll
    for (int mt = 0; mt < 4; ++mt)
#pragma unroll
        for (int reg = 0; reg < 4; ++reg) rs[mt][reg] = 0.f;

    f16x8 bf[4], bn[4];
#pragma unroll
    for (int kc = 0; kc < 4; ++kc) bf[kc] = *(const f16x8*)(kb + kc * 32);

    // ---- pass 1: row sums of relu(sim)^2 ----
    for (int ct = 0; ct < 64; ++ct) {
        const size_t noff = (size_t)(((ct + 1) & 63) * 64) * QKD;
#pragma unroll
        for (int kc = 0; kc < 4; ++kc) bn[kc] = *(const f16x8*)(kb + noff + kc * 32);

        f32x4 acc[4];
#pragma unroll
        for (int mt = 0; mt < 4; ++mt) acc[mt] = (f32x4){0.f, 0.f, 0.f, 0.f};
#pragma unroll
        for (int kc = 0; kc < 4; ++kc)
#pragma unroll
            for (int mt = 0; mt < 4; ++mt)
                acc[mt] = __builtin_amdgcn_mfma_f32_16x16x32_f16(aq[mt][kc], bf[kc], acc[mt], 0, 0, 0);
#pragma unroll
        for (int mt = 0; mt < 4; ++mt)
#pragma unroll
            for (int reg = 0; reg < 4; ++reg) {
                const float t = fmaxf(acc[mt][reg], 0.f);
                rs[mt][reg] = fmaf(t, t, rs[mt][reg]);
            }
#pragma unroll
        for (int kc = 0; kc < 4; ++kc) bf[kc] = bn[kc];
    }

    // reduce rowsums across the 16 columns held by lanes 0..15 of each quad
#pragma unroll
    for (int mt = 0; mt < 4; ++mt)
#pragma unroll
        for (int reg = 0; reg < 4; ++reg) {
            float v = rs[mt][reg];
            v += __shfl_xor(v, 1);
            v += __shfl_xor(v, 2);
            v += __shfl_xor(v, 4);
            v += __shfl_xor(v, 8);
            if (lcol == 0) partial[wave][mt * 16 + quad * 4 + reg] = v;
        }
    __syncthreads();
    if (threadIdx.x < 64) {
        const float t = partial[0][threadIdx.x] + partial[1][threadIdx.x]
                      + partial[2][threadIdx.x] + partial[3][threadIdx.x];
        scale_s[threadIdx.x] = 1.0f / (t + 1e-6f);
    }
    __syncthreads();

    float sc[4][4];
#pragma unroll
    for (int mt = 0; mt < 4; ++mt)
#pragma unroll
        for (int reg = 0; reg < 4; ++reg)
            sc[mt][reg] = scale_s[mt * 16 + quad * 4 + reg];

    // ---- pass 2: recompute (bit-identical) + normalize + store ----
    float* ob = out + ((size_t)batch * SEQ + r0) * SEQ;
    const int col0 = wave * 16 + lcol;

#pragma unroll
    for (int kc = 0; kc < 4; ++kc) bf[kc] = *(const f16x8*)(kb + kc * 32);

    for (int ct = 0; ct < 64; ++ct) {
        const size_t noff = (size_t)(((ct + 1) & 63) * 64) * QKD;
#pragma unroll
        for (int kc = 0; kc < 4; ++kc) bn[kc] = *(const f16x8*)(kb + noff + kc * 32);

        f32x4 acc[4];
#pragma unroll
        for (int mt = 0; mt < 4; ++mt) acc[mt] = (f32x4){0.f, 0.f, 0.f, 0.f};
#pragma unroll
        for (int kc = 0; kc < 4; ++kc)
#pragma unroll
            for (int mt = 0; mt < 4; ++mt)
                acc[mt] = __builtin_amdgcn_mfma_f32_16x16x32_f16(aq[mt][kc], bf[kc], acc[mt], 0, 0, 0);

        const int col = ct * 64 + col0;
#pragma unroll
        for (int mt = 0; mt < 4; ++mt)
#pragma unroll
            for (int reg = 0; reg < 4; ++reg) {
                const float t = fmaxf(acc[mt][reg], 0.f);
                const int row = mt * 16 + quad * 4 + reg;
                ob[(size_t)row * SEQ + col] = t * t * sc[mt][reg];
            }
#pragma unroll
        for (int kc = 0; kc < 4; ++kc) bf[kc] = bn[kc];
    }
}

extern "C" void kernel_launch(void* const* d_in, const int* in_sizes, int n_in,
                              void* d_out, int out_size, void* d_ws, size_t ws_size,
                              hipStream_t stream) {
    const float* x     = (const float*)d_in[0];
    const float* ln_w  = (const float*)d_in[1];
    const float* ln_b  = (const float*)d_in[2];
    const float* w_qk  = (const float*)d_in[3];
    const float* b_qk  = (const float*)d_in[4];
    const float* gamma = (const float*)d_in[5];
    const float* beta  = (const float*)d_in[6];
    float* out = (float*)d_out;

    _Float16* q_h = (_Float16*)d_ws;                       // 4 MB
    _Float16* k_h = q_h + (size_t)BATCH * SEQ * QKD;       // 4 MB

    hipLaunchKernelGGL(ln_qk_kernel, dim3((BATCH * SEQ) / 32), dim3(256), 0, stream,
                       x, ln_w, ln_b, w_qk, b_qk, gamma, beta, q_h, k_h);
    hipLaunchKernelGGL(attn_kernel, dim3(BATCH * (SEQ / 64)), dim3(256), 0, stream,
                       q_h, k_h, out);
}

// Round 2
// 403.248 us; speedup vs baseline: 1.0530x; 1.0530x over previous
//
#include <hip/hip_runtime.h>

#define DIM 512
#define QKD 128
#define BATCH 4
#define SEQ 4096

typedef __attribute__((ext_vector_type(8)))  _Float16 f16x8;
typedef __attribute__((ext_vector_type(4)))  _Float16 f16x4;
typedef __attribute__((ext_vector_type(4)))  float    f32x4;
typedef __attribute__((ext_vector_type(16))) float    f32x16;

// ---------------------------------------------------------------------------
// Prep: w_qk fp32 -> fp16 once (128x512 = 64K elems). 64 blocks x 256 thr x 4.
// ---------------------------------------------------------------------------
__global__ __launch_bounds__(256) void wcvt_kernel(
    const float* __restrict__ w, _Float16* __restrict__ w16)
{
    const int i = (blockIdx.x * 256 + threadIdx.x) * 4;
    const float4 v = *(const float4*)(w + i);
    f16x4 o;
    o[0] = (_Float16)v.x; o[1] = (_Float16)v.y;
    o[2] = (_Float16)v.z; o[3] = (_Float16)v.w;
    *(f16x4*)(w16 + i) = o;
}

// ---------------------------------------------------------------------------
// Kernel A: LayerNorm + Linear(512->128) + SiLU + OffsetScale -> q,k (fp16)
// 32 rows per block, 256 threads (4 waves). Weights pre-converted to fp16.
// Folds 1/sqrt(4096) = 1/64 as 1/8 into BOTH q and k (exact pow2 scaling).
// ---------------------------------------------------------------------------
__global__ __launch_bounds__(256) void ln_qk_kernel(
    const float* __restrict__ x,
    const float* __restrict__ ln_w,
    const float* __restrict__ ln_b,
    const _Float16* __restrict__ w16,
    const float* __restrict__ b_qk,
    const float* __restrict__ gamma,
    const float* __restrict__ beta,
    _Float16* __restrict__ q_h,
    _Float16* __restrict__ k_h)
{
    __shared__ _Float16 As[32][520];   // 520-halfs stride: 16B-aligned rows
    const int tid  = threadIdx.x;
    const int wave = tid >> 6;
    const int lane = tid & 63;
    const int row0 = blockIdx.x * 32;

    // per-lane LN params for d = lane*8 .. +7
    float lw[8], lb[8];
    {
        const float4* w4 = (const float4*)ln_w;
        const float4* b4 = (const float4*)ln_b;
        float4 w0 = w4[lane * 2], w1 = w4[lane * 2 + 1];
        float4 b0 = b4[lane * 2], b1 = b4[lane * 2 + 1];
        lw[0]=w0.x; lw[1]=w0.y; lw[2]=w0.z; lw[3]=w0.w;
        lw[4]=w1.x; lw[5]=w1.y; lw[6]=w1.z; lw[7]=w1.w;
        lb[0]=b0.x; lb[1]=b0.y; lb[2]=b0.z; lb[3]=b0.w;
        lb[4]=b1.x; lb[5]=b1.y; lb[6]=b1.z; lb[7]=b1.w;
    }

    // LayerNorm: each wave handles 8 rows
    for (int rr = 0; rr < 8; ++rr) {
        const int r = wave * 8 + rr;
        const float4* xr = (const float4*)(x + (size_t)(row0 + r) * DIM);
        float4 v0 = xr[lane * 2], v1 = xr[lane * 2 + 1];
        float xv[8] = {v0.x, v0.y, v0.z, v0.w, v1.x, v1.y, v1.z, v1.w};
        float s = 0.f, s2 = 0.f;
#pragma unroll
        for (int j = 0; j < 8; ++j) { s += xv[j]; s2 = fmaf(xv[j], xv[j], s2); }
#pragma unroll
        for (int off = 32; off > 0; off >>= 1) {
            s  += __shfl_xor(s,  off);
            s2 += __shfl_xor(s2, off);
        }
        const float mu   = s * (1.f / DIM);
        const float var  = s2 * (1.f / DIM) - mu * mu;
        const float rstd = rsqrtf(var + 1e-5f);
        f16x8 hh;
#pragma unroll
        for (int j = 0; j < 8; ++j)
            hh[j] = (_Float16)(fmaf((xv[j] - mu) * rstd, lw[j], lb[j]));
        *(f16x8*)&As[r][lane * 8] = hh;
    }
    __syncthreads();

    // GEMM: M=32 (2 m-tiles of 16), N=128 (2 n-halves of 64), 16x16x32 MFMA.
    const int mtile = wave & 1;
    const int nbase = (wave >> 1) * 64;
    const int lcol  = lane & 15;
    const int quad  = lane >> 4;

    f32x4 acc[4];
#pragma unroll
    for (int nt = 0; nt < 4; ++nt) acc[nt] = (f32x4){0.f, 0.f, 0.f, 0.f};

    const _Float16* arow = &As[mtile * 16 + lcol][quad * 8];
#pragma unroll 4
    for (int kc = 0; kc < 16; ++kc) {
        const f16x8 af = *(const f16x8*)(arow + kc * 32);
#pragma unroll
        for (int nt = 0; nt < 4; ++nt) {
            const int e = nbase + nt * 16 + lcol;
            const f16x8 bfr = *(const f16x8*)(w16 + (size_t)e * DIM + kc * 32 + quad * 8);
            acc[nt] = __builtin_amdgcn_mfma_f32_16x16x32_f16(af, bfr, acc[nt], 0, 0, 0);
        }
    }

    // epilogue: bias + SiLU + offset-scale (scaled by 1/8), store fp16
#pragma unroll
    for (int nt = 0; nt < 4; ++nt) {
        const int e = nbase + nt * 16 + lcol;
        const float bq  = b_qk[e];
        const float g0  = gamma[e]       * 0.125f;
        const float g1  = gamma[QKD + e] * 0.125f;
        const float be0 = beta[e]        * 0.125f;
        const float be1 = beta[QKD + e]  * 0.125f;
#pragma unroll
        for (int reg = 0; reg < 4; ++reg) {
            const int m  = mtile * 16 + quad * 4 + reg;
            const float v   = acc[nt][reg] + bq;
            const float sil = v / (1.f + __expf(-v));
            const size_t off = (size_t)(row0 + m) * QKD + e;
            q_h[off] = (_Float16)fmaf(sil, g0, be0);
            k_h[off] = (_Float16)fmaf(sil, g1, be1);
        }
    }
}

// ---------------------------------------------------------------------------
// Kernel B: sim = q.k^T (1/64 pre-folded), attn = relu(sim)^2 row-normalized.
// 32 rows/block, 512 blocks (2 blocks/CU), 32x32x16 MFMA. Two-pass recompute.
// q fragments register-resident; k fragments double-buffered from L2.
// Out written nontemporal (don't evict k from L2 with 268 MB of streaming).
// ---------------------------------------------------------------------------
__global__ __launch_bounds__(256) void attn_kernel(
    const _Float16* __restrict__ q_h,
    const _Float16* __restrict__ k_h,
    float* __restrict__ out)
{
    // XCD swizzle (round-robin l%8 -> XCD): each XCD sees 1 batch -> k stays
    // L2-resident (1 MB per batch per pass).
    const int l     = blockIdx.x;
    const int batch = (l & 7) >> 1;
    const int tile  = ((l >> 3) << 1) | (l & 1);
    const int r0    = tile * 32;

    const int wid  = threadIdx.x >> 6;
    const int lane = threadIdx.x & 63;
    const int n    = lane & 31;     // MFMA n / m lane index
    const int h    = lane >> 5;     // k-half selector

    // q fragments: A[m = n][k = h*8 + j], 8 k-chunks of 16 -> 32 VGPRs
    const _Float16* qb = q_h + ((size_t)batch * SEQ + r0) * QKD;
    f16x8 aq[8];
#pragma unroll
    for (int kc = 0; kc < 8; ++kc)
        aq[kc] = *(const f16x8*)(qb + (size_t)n * QKD + kc * 16 + h * 8);

    // k base: this wave's 32-col subtile; iter ct covers cols ct*128 + wid*32 + n
    const _Float16* kb = k_h + (size_t)batch * SEQ * QKD
                             + (size_t)(wid * 32 + n) * QKD + h * 8;

    __shared__ float partial[4][32];
    __shared__ float srow_s[32];

    float rs[16];
#pragma unroll
    for (int r = 0; r < 16; ++r) rs[r] = 0.f;

    f16x8 bf[8], bn[8];
#pragma unroll
    for (int kc = 0; kc < 8; ++kc) bf[kc] = *(const f16x8*)(kb + kc * 16);

    // ---- pass 1: row sums of relu(sim)^2 ----
    for (int ct = 0; ct < 32; ++ct) {
        const _Float16* nb = kb + (size_t)(((ct + 1) & 31) * 128) * QKD;
#pragma unroll
        for (int kc = 0; kc < 8; ++kc) bn[kc] = *(const f16x8*)(nb + kc * 16);

        f32x16 acc;
#pragma unroll
        for (int r = 0; r < 16; ++r) acc[r] = 0.f;
#pragma unroll
        for (int kc = 0; kc < 8; ++kc)
            acc = __builtin_amdgcn_mfma_f32_32x32x16_f16(aq[kc], bf[kc], acc, 0, 0, 0);
#pragma unroll
        for (int r = 0; r < 16; ++r) {
            const float t = fmaxf(acc[r], 0.f);
            rs[r] = fmaf(t, t, rs[r]);
        }
#pragma unroll
        for (int kc = 0; kc < 8; ++kc) bf[kc] = bn[kc];
    }

    // reduce row sums across the 32 n-lanes, then across the 4 waves
#pragma unroll
    for (int r = 0; r < 16; ++r) {
        float v = rs[r];
        v += __shfl_xor(v, 1);
        v += __shfl_xor(v, 2);
        v += __shfl_xor(v, 4);
        v += __shfl_xor(v, 8);
        v += __shfl_xor(v, 16);
        if (n == 0) partial[wid][(r & 3) + 8 * (r >> 2) + 4 * h] = v;
    }
    __syncthreads();
    if (threadIdx.x < 32) {
        const float t = partial[0][threadIdx.x] + partial[1][threadIdx.x]
                      + partial[2][threadIdx.x] + partial[3][threadIdx.x];
        srow_s[threadIdx.x] = rsqrtf(t + 1e-6f);   // out = (t*srow)^2 = t^2/(sum+1e-6)
    }
    __syncthreads();

    float srow[16];
#pragma unroll
    for (int r = 0; r < 16; ++r)
        srow[r] = srow_s[(r & 3) + 8 * (r >> 2) + 4 * h];

    // ---- pass 2: recompute (bit-identical) + normalize + nontemporal store ----
    float* ob = out + ((size_t)batch * SEQ + r0) * SEQ;

#pragma unroll
    for (int kc = 0; kc < 8; ++kc) bf[kc] = *(const f16x8*)(kb + kc * 16);

    for (int ct = 0; ct < 32; ++ct) {
        const _Float16* nb = kb + (size_t)(((ct + 1) & 31) * 128) * QKD;
#pragma unroll
        for (int kc = 0; kc < 8; ++kc) bn[kc] = *(const f16x8*)(nb + kc * 16);

        f32x16 acc;
#pragma unroll
        for (int r = 0; r < 16; ++r) acc[r] = 0.f;
#pragma unroll
        for (int kc = 0; kc < 8; ++kc)
            acc = __builtin_amdgcn_mfma_f32_32x32x16_f16(aq[kc], bf[kc], acc, 0, 0, 0);

        const int col = ct * 128 + wid * 32 + n;
#pragma unroll
        for (int r = 0; r < 16; ++r) {
            const float t   = fmaxf(acc[r], 0.f) * srow[r];
            const int   row = (r & 3) + 8 * (r >> 2) + 4 * h;
            __builtin_nontemporal_store(t * t, ob + (size_t)row * SEQ + col);
        }
#pragma unroll
        for (int kc = 0; kc < 8; ++kc) bf[kc] = bn[kc];
    }
}

extern "C" void kernel_launch(void* const* d_in, const int* in_sizes, int n_in,
                              void* d_out, int out_size, void* d_ws, size_t ws_size,
                              hipStream_t stream) {
    const float* x     = (const float*)d_in[0];
    const float* ln_w  = (const float*)d_in[1];
    const float* ln_b  = (const float*)d_in[2];
    const float* w_qk  = (const float*)d_in[3];
    const float* b_qk  = (const float*)d_in[4];
    const float* gamma = (const float*)d_in[5];
    const float* beta  = (const float*)d_in[6];
    float* out = (float*)d_out;

    _Float16* q_h = (_Float16*)d_ws;                            // 4 MB
    _Float16* k_h = q_h + (size_t)BATCH * SEQ * QKD;            // 4 MB
    _Float16* w16 = k_h + (size_t)BATCH * SEQ * QKD;            // 128 KB

    hipLaunchKernelGGL(wcvt_kernel, dim3(64), dim3(256), 0, stream, w_qk, w16);
    hipLaunchKernelGGL(ln_qk_kernel, dim3((BATCH * SEQ) / 32), dim3(256), 0, stream,
                       x, ln_w, ln_b, w16, b_qk, gamma, beta, q_h, k_h);
    hipLaunchKernelGGL(attn_kernel, dim3(BATCH * (SEQ / 32)), dim3(256), 0, stream,
                       q_h, k_h, out);
}

// Round 3
// 398.170 us; speedup vs baseline: 1.0665x; 1.0128x over previous
//
#include <hip/hip_runtime.h>

#define DIM 512
#define QKD 128
#define BATCH 4
#define SEQ 4096

typedef __attribute__((ext_vector_type(8)))  _Float16 f16x8;
typedef __attribute__((ext_vector_type(4)))  _Float16 f16x4;
typedef __attribute__((ext_vector_type(4)))  float    f32x4;
typedef __attribute__((ext_vector_type(16))) float    f32x16;

// ---------------------------------------------------------------------------
// Prep: w_qk fp32 -> fp16 once (128x512 = 64K elems). 64 blocks x 256 thr x 4.
// ---------------------------------------------------------------------------
__global__ __launch_bounds__(256) void wcvt_kernel(
    const float* __restrict__ w, _Float16* __restrict__ w16)
{
    const int i = (blockIdx.x * 256 + threadIdx.x) * 4;
    const float4 v = *(const float4*)(w + i);
    f16x4 o;
    o[0] = (_Float16)v.x; o[1] = (_Float16)v.y;
    o[2] = (_Float16)v.z; o[3] = (_Float16)v.w;
    *(f16x4*)(w16 + i) = o;
}

// ---------------------------------------------------------------------------
// Kernel A: LayerNorm + Linear(512->128) + SiLU + OffsetScale -> q,k (fp16)
// 32 rows per block, 256 threads (4 waves). Weights pre-converted to fp16.
// Folds 1/sqrt(4096) = 1/64 as 1/8 into BOTH q and k (exact pow2 scaling).
// ---------------------------------------------------------------------------
__global__ __launch_bounds__(256) void ln_qk_kernel(
    const float* __restrict__ x,
    const float* __restrict__ ln_w,
    const float* __restrict__ ln_b,
    const _Float16* __restrict__ w16,
    const float* __restrict__ b_qk,
    const float* __restrict__ gamma,
    const float* __restrict__ beta,
    _Float16* __restrict__ q_h,
    _Float16* __restrict__ k_h)
{
    __shared__ _Float16 As[32][520];   // 520-halfs stride: 16B-aligned rows
    const int tid  = threadIdx.x;
    const int wave = tid >> 6;
    const int lane = tid & 63;
    const int row0 = blockIdx.x * 32;

    // per-lane LN params for d = lane*8 .. +7
    float lw[8], lb[8];
    {
        const float4* w4 = (const float4*)ln_w;
        const float4* b4 = (const float4*)ln_b;
        float4 w0 = w4[lane * 2], w1 = w4[lane * 2 + 1];
        float4 b0 = b4[lane * 2], b1 = b4[lane * 2 + 1];
        lw[0]=w0.x; lw[1]=w0.y; lw[2]=w0.z; lw[3]=w0.w;
        lw[4]=w1.x; lw[5]=w1.y; lw[6]=w1.z; lw[7]=w1.w;
        lb[0]=b0.x; lb[1]=b0.y; lb[2]=b0.z; lb[3]=b0.w;
        lb[4]=b1.x; lb[5]=b1.y; lb[6]=b1.z; lb[7]=b1.w;
    }

    // LayerNorm: each wave handles 8 rows
    for (int rr = 0; rr < 8; ++rr) {
        const int r = wave * 8 + rr;
        const float4* xr = (const float4*)(x + (size_t)(row0 + r) * DIM);
        float4 v0 = xr[lane * 2], v1 = xr[lane * 2 + 1];
        float xv[8] = {v0.x, v0.y, v0.z, v0.w, v1.x, v1.y, v1.z, v1.w};
        float s = 0.f, s2 = 0.f;
#pragma unroll
        for (int j = 0; j < 8; ++j) { s += xv[j]; s2 = fmaf(xv[j], xv[j], s2); }
#pragma unroll
        for (int off = 32; off > 0; off >>= 1) {
            s  += __shfl_xor(s,  off);
            s2 += __shfl_xor(s2, off);
        }
        const float mu   = s * (1.f / DIM);
        const float var  = s2 * (1.f / DIM) - mu * mu;
        const float rstd = rsqrtf(var + 1e-5f);
        f16x8 hh;
#pragma unroll
        for (int j = 0; j < 8; ++j)
            hh[j] = (_Float16)(fmaf((xv[j] - mu) * rstd, lw[j], lb[j]));
        *(f16x8*)&As[r][lane * 8] = hh;
    }
    __syncthreads();

    // GEMM: M=32 (2 m-tiles of 16), N=128 (2 n-halves of 64), 16x16x32 MFMA.
    const int mtile = wave & 1;
    const int nbase = (wave >> 1) * 64;
    const int lcol  = lane & 15;
    const int quad  = lane >> 4;

    f32x4 acc[4];
#pragma unroll
    for (int nt = 0; nt < 4; ++nt) acc[nt] = (f32x4){0.f, 0.f, 0.f, 0.f};

    const _Float16* arow = &As[mtile * 16 + lcol][quad * 8];
#pragma unroll 4
    for (int kc = 0; kc < 16; ++kc) {
        const f16x8 af = *(const f16x8*)(arow + kc * 32);
#pragma unroll
        for (int nt = 0; nt < 4; ++nt) {
            const int e = nbase + nt * 16 + lcol;
            const f16x8 bfr = *(const f16x8*)(w16 + (size_t)e * DIM + kc * 32 + quad * 8);
            acc[nt] = __builtin_amdgcn_mfma_f32_16x16x32_f16(af, bfr, acc[nt], 0, 0, 0);
        }
    }

    // epilogue: bias + SiLU + offset-scale (scaled by 1/8), store fp16
#pragma unroll
    for (int nt = 0; nt < 4; ++nt) {
        const int e = nbase + nt * 16 + lcol;
        const float bq  = b_qk[e];
        const float g0  = gamma[e]       * 0.125f;
        const float g1  = gamma[QKD + e] * 0.125f;
        const float be0 = beta[e]        * 0.125f;
        const float be1 = beta[QKD + e]  * 0.125f;
#pragma unroll
        for (int reg = 0; reg < 4; ++reg) {
            const int m  = mtile * 16 + quad * 4 + reg;
            const float v   = acc[nt][reg] + bq;
            const float sil = v / (1.f + __expf(-v));
            const size_t off = (size_t)(row0 + m) * QKD + e;
            q_h[off] = (_Float16)fmaf(sil, g0, be0);
            k_h[off] = (_Float16)fmaf(sil, g1, be1);
        }
    }
}

// ---------------------------------------------------------------------------
// Kernel B: sim = q.k^T (1/64 pre-folded), attn = relu(sim)^2 row-normalized.
// 32 rows/block, 512 blocks, 32x32x16 MFMA. Two-pass recompute.
// R3: dropped explicit k double-buffer (-32 VGPR), __launch_bounds__(256,3)
// to force 3 waves/SIMD; compiler software-pipelines the ct loop itself.
// ---------------------------------------------------------------------------
__global__ __launch_bounds__(256, 3) void attn_kernel(
    const _Float16* __restrict__ q_h,
    const _Float16* __restrict__ k_h,
    float* __restrict__ out)
{
    // XCD swizzle (round-robin l%8 -> XCD): each XCD sees 1 batch -> k stays
    // L2-resident (1 MB per batch per pass).
    const int l     = blockIdx.x;
    const int batch = (l & 7) >> 1;
    const int tile  = ((l >> 3) << 1) | (l & 1);
    const int r0    = tile * 32;

    const int wid  = threadIdx.x >> 6;
    const int lane = threadIdx.x & 63;
    const int n    = lane & 31;     // MFMA n / m lane index
    const int h    = lane >> 5;     // k-half selector

    // q fragments: A[m = n][k = h*8 + j], 8 k-chunks of 16 -> 32 VGPRs
    const _Float16* qb = q_h + ((size_t)batch * SEQ + r0) * QKD;
    f16x8 aq[8];
#pragma unroll
    for (int kc = 0; kc < 8; ++kc)
        aq[kc] = *(const f16x8*)(qb + (size_t)n * QKD + kc * 16 + h * 8);

    // k base: this wave's 32-col subtile; iter ct covers cols ct*128 + wid*32 + n
    const _Float16* kb = k_h + (size_t)batch * SEQ * QKD
                             + (size_t)(wid * 32 + n) * QKD + h * 8;

    __shared__ float partial[4][32];
    __shared__ float srow_s[32];

    float rs[16];
#pragma unroll
    for (int r = 0; r < 16; ++r) rs[r] = 0.f;

    // ---- pass 1: row sums of relu(sim)^2 ----
#pragma unroll 2
    for (int ct = 0; ct < 32; ++ct) {
        const _Float16* cb = kb + (size_t)(ct * 128) * QKD;
        f16x8 bf[8];
#pragma unroll
        for (int kc = 0; kc < 8; ++kc) bf[kc] = *(const f16x8*)(cb + kc * 16);

        f32x16 acc;
#pragma unroll
        for (int r = 0; r < 16; ++r) acc[r] = 0.f;
#pragma unroll
        for (int kc = 0; kc < 8; ++kc)
            acc = __builtin_amdgcn_mfma_f32_32x32x16_f16(aq[kc], bf[kc], acc, 0, 0, 0);
#pragma unroll
        for (int r = 0; r < 16; ++r) {
            const float t = fmaxf(acc[r], 0.f);
            rs[r] = fmaf(t, t, rs[r]);
        }
    }

    // reduce row sums across the 32 n-lanes, then across the 4 waves
#pragma unroll
    for (int r = 0; r < 16; ++r) {
        float v = rs[r];
        v += __shfl_xor(v, 1);
        v += __shfl_xor(v, 2);
        v += __shfl_xor(v, 4);
        v += __shfl_xor(v, 8);
        v += __shfl_xor(v, 16);
        if (n == 0) partial[wid][(r & 3) + 8 * (r >> 2) + 4 * h] = v;
    }
    __syncthreads();
    if (threadIdx.x < 32) {
        const float t = partial[0][threadIdx.x] + partial[1][threadIdx.x]
                      + partial[2][threadIdx.x] + partial[3][threadIdx.x];
        srow_s[threadIdx.x] = rsqrtf(t + 1e-6f);   // out = (t*srow)^2 = t^2/(sum+1e-6)
    }
    __syncthreads();

    float srow[16];
#pragma unroll
    for (int r = 0; r < 16; ++r)
        srow[r] = srow_s[(r & 3) + 8 * (r >> 2) + 4 * h];

    // ---- pass 2: recompute (bit-identical) + normalize + nontemporal store ----
    float* ob = out + ((size_t)batch * SEQ + r0) * SEQ;

#pragma unroll 2
    for (int ct = 0; ct < 32; ++ct) {
        const _Float16* cb = kb + (size_t)(ct * 128) * QKD;
        f16x8 bf[8];
#pragma unroll
        for (int kc = 0; kc < 8; ++kc) bf[kc] = *(const f16x8*)(cb + kc * 16);

        f32x16 acc;
#pragma unroll
        for (int r = 0; r < 16; ++r) acc[r] = 0.f;
#pragma unroll
        for (int kc = 0; kc < 8; ++kc)
            acc = __builtin_amdgcn_mfma_f32_32x32x16_f16(aq[kc], bf[kc], acc, 0, 0, 0);

        const int col = ct * 128 + wid * 32 + n;
#pragma unroll
        for (int r = 0; r < 16; ++r) {
            const float t   = fmaxf(acc[r], 0.f) * srow[r];
            const int   row = (r & 3) + 8 * (r >> 2) + 4 * h;
            __builtin_nontemporal_store(t * t, ob + (size_t)row * SEQ + col);
        }
    }
}

extern "C" void kernel_launch(void* const* d_in, const int* in_sizes, int n_in,
                              void* d_out, int out_size, void* d_ws, size_t ws_size,
                              hipStream_t stream) {
    const float* x     = (const float*)d_in[0];
    const float* ln_w  = (const float*)d_in[1];
    const float* ln_b  = (const float*)d_in[2];
    const float* w_qk  = (const float*)d_in[3];
    const float* b_qk  = (const float*)d_in[4];
    const float* gamma = (const float*)d_in[5];
    const float* beta  = (const float*)d_in[6];
    float* out = (float*)d_out;

    _Float16* q_h = (_Float16*)d_ws;                            // 4 MB
    _Float16* k_h = q_h + (size_t)BATCH * SEQ * QKD;            // 4 MB
    _Float16* w16 = k_h + (size_t)BATCH * SEQ * QKD;            // 128 KB

    hipLaunchKernelGGL(wcvt_kernel, dim3(64), dim3(256), 0, stream, w_qk, w16);
    hipLaunchKernelGGL(ln_qk_kernel, dim3((BATCH * SEQ) / 32), dim3(256), 0, stream,
                       x, ln_w, ln_b, w16, b_qk, gamma, beta, q_h, k_h);
    hipLaunchKernelGGL(attn_kernel, dim3(BATCH * (SEQ / 32)), dim3(256), 0, stream,
                       q_h, k_h, out);
}